// Round 9
// baseline (570.088 us; speedup 1.0000x reference)
//
#include <hip/hip_runtime.h>
#include <hip/hip_bf16.h>
#include <hip/hip_fp16.h>
#include <math.h>

// Problem constants
#define B_   256
#define HID_ 1024
#define SP_  2048
#define N_   196        // 14*14
#define NJ_  (B_ * N_)  // 50176 = 196 * 256
#define SPB_ (SP_ * N_) // elems per batch of spatial

typedef float    f32x4 __attribute__((ext_vector_type(4)));
typedef _Float16 f16x8 __attribute__((ext_vector_type(8)));

#define GLOBAL_AS(p) ((const __attribute__((address_space(1))) void*)(p))
#define LDS_AS(p)    ((__attribute__((address_space(3))) void*)(p))

__device__ __forceinline__ float fast_tanh(float x) {
    const float e = exp2f(x * 2.8853900817779268f);  // 2*log2(e)
    return 1.f - 2.f / (e + 1.f);
}

// ---------------------------------------------------------------------------
// K1: h1[b,d] = hidden @ W1h + b1   (256x1024 @ 1024x1024)
// ---------------------------------------------------------------------------
__global__ __launch_bounds__(256) void k1_h1(
    const float* __restrict__ hidden, const float* __restrict__ W1,
    const float* __restrict__ b1, float* __restrict__ h1)
{
    __shared__ float hs[4][HID_];
    const int t = threadIdx.x;
    const int d = blockIdx.x * 256 + t;
    const int b0 = blockIdx.y * 4;

    for (int i = t; i < 4 * HID_; i += 256)
        hs[i >> 10][i & 1023] = hidden[(size_t)(b0 + (i >> 10)) * HID_ + (i & 1023)];
    __syncthreads();

    float acc[4] = {};
    for (int h = 0; h < HID_; ++h) {
        const float w = W1[(size_t)h * HID_ + d];
#pragma unroll
        for (int i = 0; i < 4; ++i) acc[i] += hs[i][h] * w;
    }
    const float bias = b1[d];
#pragma unroll
    for (int i = 0; i < 4; ++i)
        h1[(size_t)(b0 + i) * HID_ + d] = acc[i] + bias;
}

// ---------------------------------------------------------------------------
// K0a: pack A = W1s^T (d x c, 1024x2048) into fp16 K-step chunks.
// Chunk (dt2, ks): 256 d x 32 c, layout [cg(4)][dd(256)][c8(8)] = 8192 halfs.
// ---------------------------------------------------------------------------
__global__ __launch_bounds__(256) void k0a_packA(
    const float* __restrict__ W1, __half* __restrict__ Ah)
{
    const size_t idx = (size_t)blockIdx.x * 256 + threadIdx.x;  // < 2,097,152
    const int c8 = idx & 7;
    const int dd = (idx >> 3) & 255;
    const int cg = (idx >> 11) & 3;
    const int ks = (idx >> 13) & 63;
    const int dt2 = idx >> 19;
    const int d = dt2 * 256 + dd;
    const int c = ks * 32 + cg * 8 + c8;
    Ah[idx] = __float2half(W1[(size_t)(HID_ + c) * HID_ + d]);
}

// ---------------------------------------------------------------------------
// K0b: pack B = spT (c x j) into fp16 K-step chunks — LDS-free.
// Chunk (jt2, ks): 32 c x 256 j, layout [cg(4)][jj(256)][c8(8)] = 8192 halfs.
// ---------------------------------------------------------------------------
__global__ __launch_bounds__(256) void k0b_packB(
    const float* __restrict__ spatial, __half* __restrict__ Bh)
{
    const int jt2 = blockIdx.x;           // 0..195
    const int ks  = blockIdx.y;           // 0..63
    const int jj  = threadIdx.x;          // 0..255

    const int j = jt2 * 256 + jj;
    const int b = j / N_;
    const int n = j - b * N_;
    const float* spj = spatial + (size_t)b * SPB_ + n;
    __half* outb = Bh + (((size_t)jt2 * 64 + ks) * 4) * 2048 + jj * 8;

#pragma unroll
    for (int cg = 0; cg < 4; ++cg) {
        const float* src = spj + (size_t)(ks * 32 + cg * 8) * N_;
        f16x8 v;
#pragma unroll
        for (int c8 = 0; c8 < 8; ++c8)
            v[c8] = (_Float16)src[(size_t)c8 * N_];
        *(f16x8*)(outb + (size_t)cg * 2048) = v;
    }
}

// ---------------------------------------------------------------------------
// K2 (pipelined MFMA, v2): 256x256 block tile, 4 waves (2Mx2N), per-wave
// 128x128 (square tile -> 64 KB LDS reads/CU/step vs 96 KB for 128x64 —
// the R8 kernel measured LDS-read-BW-bound at 36% MfmaUtil).
// BK=32, FULL K=2048 (64 steps). 4-slot LDS ring (128 KB), stage-ahead-2,
// counted vmcnt(16) (8 gload_lds per stage), ONE s_barrier per K-step,
// s_setprio around the 64-MFMA cluster.
// Fused epilogue: ps[dt2*NJ + j] = sum_{d in 256-range} tanh(C+h1)*w2.
// ---------------------------------------------------------------------------
__global__ __launch_bounds__(256, 1) void k2_pipe(
    const __half* __restrict__ Ah, const __half* __restrict__ Bh,
    const float* __restrict__ W2, const float* __restrict__ h1,
    float* __restrict__ ps)
{
    extern __shared__ __align__(16) short ldsb[];   // 4 * 16384 halfs = 128 KB

    const int tid = threadIdx.x;
    const int l  = tid & 63;
    const int w  = tid >> 6;            // wave 0..3
    const int wm = w >> 1;              // 0..1  (d half: 128 rows)
    const int wn = w & 1;               // 0..1  (j half: 128 cols)
    const int cg = l >> 4;              // 0..3
    const int rr = l & 15;

    // bijective XCD-chunked swizzle: 784 = 8 * 98; dt2 fastest in chunk.
    const int orig = blockIdx.x;
    const int wgid = (orig & 7) * 98 + (orig >> 3);
    const int jt2 = wgid >> 2;          // 0..195
    const int dt2 = wgid & 3;           // 0..3

    const __half* apack = Ah + ((size_t)dt2 * 64) * 8192;
    const __half* bpack = Bh + ((size_t)jt2 * 64) * 8192;

    f32x4 acc[8][8] = {};

#define STAGE(KT, SLOT) do {                                                    \
        const __half* as_ = apack + (size_t)(KT) * 8192 + w * 2048;             \
        const __half* bs_ = bpack + (size_t)(KT) * 8192 + w * 2048;             \
        short* ad_ = ldsb + (SLOT) * 16384 + w * 2048;                          \
        short* bd_ = ldsb + (SLOT) * 16384 + 8192 + w * 2048;                   \
        _Pragma("unroll")                                                       \
        for (int i_ = 0; i_ < 4; ++i_) {                                        \
            __builtin_amdgcn_global_load_lds(GLOBAL_AS(as_ + i_ * 512 + l * 8), \
                                             LDS_AS(ad_ + i_ * 512), 16, 0, 0); \
            __builtin_amdgcn_global_load_lds(GLOBAL_AS(bs_ + i_ * 512 + l * 8), \
                                             LDS_AS(bd_ + i_ * 512), 16, 0, 0); \
        }                                                                       \
    } while (0)

#define COMPUTE(SLOT) do {                                                      \
        const short* ab_ = ldsb + (SLOT) * 16384;                               \
        const short* bb_ = ab_ + 8192;                                          \
        f16x8 af[8], bf[8];                                                     \
        _Pragma("unroll")                                                       \
        for (int mi = 0; mi < 8; ++mi)                                          \
            af[mi] = *(const f16x8*)&ab_[(cg * 256 + wm * 128 + mi * 16 + rr) * 8];\
        _Pragma("unroll")                                                       \
        for (int ni = 0; ni < 8; ++ni)                                          \
            bf[ni] = *(const f16x8*)&bb_[(cg * 256 + wn * 128 + ni * 16 + rr) * 8];\
        __builtin_amdgcn_s_setprio(1);                                          \
        _Pragma("unroll")                                                       \
        for (int mi = 0; mi < 8; ++mi)                                          \
            _Pragma("unroll")                                                   \
            for (int ni = 0; ni < 8; ++ni)                                      \
                acc[mi][ni] = __builtin_amdgcn_mfma_f32_16x16x32_f16(           \
                    af[mi], bf[ni], acc[mi][ni], 0, 0, 0);                      \
        __builtin_amdgcn_s_setprio(0);                                          \
    } while (0)

#define STEP(KS, SSLOT, CSLOT, VMC) do {                                        \
        STAGE(KS, SSLOT);                                                       \
        asm volatile("s_waitcnt vmcnt(" #VMC ")" ::: "memory");                 \
        __builtin_amdgcn_s_barrier();                                           \
        __builtin_amdgcn_sched_barrier(0);                                      \
        COMPUTE(CSLOT);                                                         \
    } while (0)

    STAGE(0, 0);
    STAGE(1, 1);
#pragma unroll 1
    for (int kt = 0; kt < 60; kt += 4) {
        STEP(kt + 2, 2, 0, 16);
        STEP(kt + 3, 3, 1, 16);
        STEP(kt + 4, 0, 2, 16);
        STEP(kt + 5, 1, 3, 16);
    }
    // tail: stages 62,63; computes 60..63
    STEP(62, 2, 0, 16);
    STEP(63, 3, 1, 16);
    asm volatile("s_waitcnt vmcnt(8)" ::: "memory");
    __builtin_amdgcn_s_barrier();
    __builtin_amdgcn_sched_barrier(0);
    COMPUTE(2);
    asm volatile("s_waitcnt vmcnt(0)" ::: "memory");
    __builtin_amdgcn_s_barrier();
    __builtin_amdgcn_sched_barrier(0);
    COMPUTE(3);

#undef STAGE
#undef COMPUTE
#undef STEP

    // Epilogue: partial[j] = sum_{d in this block's 256} tanh(acc + h1) * w2
    const int dbase = dt2 * 256 + wm * 128;
    float w2v[8][4];
#pragma unroll
    for (int mi = 0; mi < 8; ++mi)
#pragma unroll
        for (int q = 0; q < 4; ++q)
            w2v[mi][q] = W2[dbase + mi * 16 + cg * 4 + q];

    float partial[8];
#pragma unroll
    for (int ni = 0; ni < 8; ++ni) {
        const int j = jt2 * 256 + wn * 128 + ni * 16 + rr;
        const int bj = j / N_;
        const float* h1p = h1 + (size_t)bj * HID_ + dbase;
        float s = 0.f;
#pragma unroll
        for (int mi = 0; mi < 8; ++mi)
#pragma unroll
            for (int q = 0; q < 4; ++q)
                s += fast_tanh(acc[mi][ni][q] + h1p[mi * 16 + cg * 4 + q]) * w2v[mi][q];
        partial[ni] = s;
    }

    float* red = (float*)ldsb;
    __syncthreads();                 // all waves done with ring LDS reads
    red[tid] = 0.f;
    __syncthreads();
#pragma unroll
    for (int ni = 0; ni < 8; ++ni)
        atomicAdd(&red[wn * 128 + ni * 16 + rr], partial[ni]);
    __syncthreads();
    ps[(size_t)dt2 * NJ_ + (size_t)jt2 * 256 + tid] = red[tid];
}

// ---------------------------------------------------------------------------
// K2 fallback (fp32 vector path) if workspace is too small for packing.
// ---------------------------------------------------------------------------
__global__ __launch_bounds__(256) void k2_fb(
    const float* __restrict__ spatial, const float* __restrict__ W1,
    const float* __restrict__ W2, const float* __restrict__ h1,
    float* __restrict__ ps)
{
    __shared__ float As[32][64];
    __shared__ float Bs[32][64];
    const int t = threadIdx.x;
    const int d0 = blockIdx.x * 64;
    const int j0 = blockIdx.y * 64;
    const int ld = t & 63, lk = t >> 6;
    const float* Aptr = W1 + (size_t)(HID_ + lk) * HID_ + (d0 + ld);
    const int j = j0 + ld;
    const int bb = j / N_, nn = j - bb * N_;
    const float* Bptr = spatial + (size_t)bb * SPB_ + (size_t)lk * N_ + nn;
    const int tr = t >> 4, tc = t & 15;
    float acc[4][4] = {};
    for (int c0 = 0; c0 < SP_; c0 += 32) {
#pragma unroll
        for (int i = 0; i < 8; ++i) {
            As[lk + 4 * i][ld] = Aptr[(size_t)(c0 + 4 * i) * HID_];
            Bs[lk + 4 * i][ld] = Bptr[(size_t)(c0 + 4 * i) * N_];
        }
        __syncthreads();
#pragma unroll
        for (int k = 0; k < 32; ++k) {
            float av[4], bv[4];
            *(float4*)av = *(const float4*)&As[k][tr * 4];
            *(float4*)bv = *(const float4*)&Bs[k][tc * 4];
#pragma unroll
            for (int di = 0; di < 4; ++di)
#pragma unroll
                for (int ji = 0; ji < 4; ++ji)
                    acc[di][ji] += av[di] * bv[ji];
        }
        __syncthreads();
    }
    float w2v[4];
#pragma unroll
    for (int di = 0; di < 4; ++di) w2v[di] = W2[d0 + tr * 4 + di];
    float partial[4] = {};
#pragma unroll
    for (int ji = 0; ji < 4; ++ji) {
        const int jg = j0 + tc * 4 + ji;
        const int bj = jg / N_;
        const float* h1row = h1 + (size_t)bj * HID_ + d0 + tr * 4;
#pragma unroll
        for (int di = 0; di < 4; ++di)
            partial[ji] += tanhf(acc[di][ji] + h1row[di]) * w2v[di];
    }
    __shared__ float red[64];
    if (t < 64) red[t] = 0.f;
    __syncthreads();
#pragma unroll
    for (int ji = 0; ji < 4; ++ji)
        atomicAdd(&red[tc * 4 + ji], partial[ji]);
    __syncthreads();
    if (t < 64)
        ps[(size_t)blockIdx.x * NJ_ + j0 + t] = red[t];
}

// ---------------------------------------------------------------------------
// K3: scores[b,n] = sum_slices ps; attn = softmax_n  (b2 shift-invariant)
// ---------------------------------------------------------------------------
__global__ __launch_bounds__(256) void k3_softmax(
    const float* __restrict__ ps, float* __restrict__ attn, int nslices)
{
    const int b = blockIdx.x;
    const int t = threadIdx.x;
    __shared__ float sdata[256];

    float s = -1e30f;
    if (t < N_) {
        s = 0.f;
        for (int dt = 0; dt < nslices; ++dt)
            s += ps[(size_t)dt * NJ_ + b * N_ + t];
    }
    sdata[t] = s;
    __syncthreads();
    for (int off = 128; off > 0; off >>= 1) {
        if (t < off) sdata[t] = fmaxf(sdata[t], sdata[t + off]);
        __syncthreads();
    }
    const float m = sdata[0];
    __syncthreads();
    const float e = (t < N_) ? expf(s - m) : 0.f;
    sdata[t] = e;
    __syncthreads();
    for (int off = 128; off > 0; off >>= 1) {
        if (t < off) sdata[t] += sdata[t + off];
        __syncthreads();
    }
    const float inv = 1.f / sdata[0];
    if (t < N_) attn[(size_t)b * N_ + t] = e * inv;
}

// ---------------------------------------------------------------------------
// K4: context[b,c] = sum_n attn[b,n] * spatial[b, c*196 + n]
// 196 = 49 float4 (row base 784 B, 16B-aligned). One wave per (b,c).
// ---------------------------------------------------------------------------
__global__ __launch_bounds__(256) void k4_context(
    const float* __restrict__ spatial, const float* __restrict__ attn,
    float* __restrict__ ctx)
{
    const int wid = (blockIdx.x * 256 + threadIdx.x) >> 6;
    const int lane = threadIdx.x & 63;
    const int b = wid >> 11;
    const int c = wid & 2047;
    const float* sp = spatial + (size_t)b * SPB_ + (size_t)c * N_;
    const float* at = attn + (size_t)b * N_;

    float sum = 0.f;
    if (lane < 49) {
        const float4 s4 = ((const float4*)sp)[lane];
        const float4 a4 = ((const float4*)at)[lane];
        sum = s4.x * a4.x + s4.y * a4.y + s4.z * a4.z + s4.w * a4.w;
    }
#pragma unroll
    for (int off = 32; off > 0; off >>= 1)
        sum += __shfl_down(sum, off, 64);
    if (lane == 0)
        ctx[(size_t)b * 2048 + c] = sum;
}

// ---------------------------------------------------------------------------
extern "C" void kernel_launch(void* const* d_in, const int* in_sizes, int n_in,
                              void* d_out, int out_size, void* d_ws, size_t ws_size,
                              hipStream_t stream)
{
    const float* hidden  = (const float*)d_in[0];
    const float* spatial = (const float*)d_in[1];
    const float* W1      = (const float*)d_in[2];
    const float* b1      = (const float*)d_in[3];
    const float* W2      = (const float*)d_in[4];
    // b2 unused: softmax shift-invariant.

    float* out_ctx  = (float*)d_out;
    float* out_attn = (float*)d_out + (size_t)B_ * 2048;

    char* ws = (char*)d_ws;
    float* h1 = (float*)ws;                               // 1 MB
    float* psb = (float*)(ws + (1u << 20));               // 4-16 slices (3.2 MB)

    // MFMA-path workspace layout
    const size_t offAh = 8u << 20;                         // 4 MB
    const size_t offBh = 16u << 20;                        // 205 MB
    const size_t szB   = (size_t)196 * 64 * 8192 * 2;      // 205,520,896 B
    const size_t needed = offBh + szB;                     // ~212 MB

    k1_h1<<<dim3(4, 64), 256, 0, stream>>>(hidden, W1, b1, h1);

    if (ws_size >= needed) {
        __half* Ah = (__half*)(ws + offAh);
        __half* Bh = (__half*)(ws + offBh);
        k0a_packA<<<dim3(8192), 256, 0, stream>>>(W1, Ah);
        k0b_packB<<<dim3(196, 64), 256, 0, stream>>>(spatial, Bh);
        (void)hipFuncSetAttribute((const void*)k2_pipe,
                                  hipFuncAttributeMaxDynamicSharedMemorySize,
                                  131072);
        k2_pipe<<<dim3(784), 256, 131072, stream>>>(Ah, Bh, W2, h1, psb);
        k3_softmax<<<dim3(B_), 256, 0, stream>>>(psb, out_attn, 4);
    } else {
        k2_fb<<<dim3(16, 784), 256, 0, stream>>>(spatial, W1, W2, h1, psb);
        k3_softmax<<<dim3(B_), 256, 0, stream>>>(psb, out_attn, 16);
    }
    k4_context<<<dim3((B_ * 2048) / 4), 256, 0, stream>>>(spatial, out_attn, out_ctx);
}

// Round 11
// 539.138 us; speedup vs baseline: 1.0574x; 1.0574x over previous
//
#include <hip/hip_runtime.h>
#include <hip/hip_bf16.h>
#include <hip/hip_fp16.h>
#include <math.h>

// Problem constants
#define B_   256
#define HID_ 1024
#define SP_  2048
#define N_   196        // 14*14
#define NJ_  (B_ * N_)  // 50176 = 196 * 256
#define SPB_ (SP_ * N_) // elems per batch of spatial

typedef float    f32x4 __attribute__((ext_vector_type(4)));
typedef _Float16 f16x8 __attribute__((ext_vector_type(8)));

#define GLOBAL_AS(p) ((const __attribute__((address_space(1))) void*)(p))
#define LDS_AS(p)    ((__attribute__((address_space(3))) void*)(p))

__device__ __forceinline__ float fast_tanh(float x) {
    const float e = exp2f(x * 2.8853900817779268f);  // 2*log2(e)
    return 1.f - 2.f / (e + 1.f);
}

// ---------------------------------------------------------------------------
// K1: h1[b,d] = hidden @ W1h + b1   (256x1024 @ 1024x1024)
// ---------------------------------------------------------------------------
__global__ __launch_bounds__(256) void k1_h1(
    const float* __restrict__ hidden, const float* __restrict__ W1,
    const float* __restrict__ b1, float* __restrict__ h1)
{
    __shared__ float hs[4][HID_];
    const int t = threadIdx.x;
    const int d = blockIdx.x * 256 + t;
    const int b0 = blockIdx.y * 4;

    for (int i = t; i < 4 * HID_; i += 256)
        hs[i >> 10][i & 1023] = hidden[(size_t)(b0 + (i >> 10)) * HID_ + (i & 1023)];
    __syncthreads();

    float acc[4] = {};
    for (int h = 0; h < HID_; ++h) {
        const float w = W1[(size_t)h * HID_ + d];
#pragma unroll
        for (int i = 0; i < 4; ++i) acc[i] += hs[i][h] * w;
    }
    const float bias = b1[d];
#pragma unroll
    for (int i = 0; i < 4; ++i)
        h1[(size_t)(b0 + i) * HID_ + d] = acc[i] + bias;
}

// ---------------------------------------------------------------------------
// K0a: pack A = W1s^T (d x c, 1024x2048) into fp16 K-step chunks.
// Chunk (dt2, ks): 256 d x 32 c, layout [cg(4)][dd(256)][c8(8)] = 8192 halfs.
// ---------------------------------------------------------------------------
__global__ __launch_bounds__(256) void k0a_packA(
    const float* __restrict__ W1, __half* __restrict__ Ah)
{
    const size_t idx = (size_t)blockIdx.x * 256 + threadIdx.x;  // < 2,097,152
    const int c8 = idx & 7;
    const int dd = (idx >> 3) & 255;
    const int cg = (idx >> 11) & 3;
    const int ks = (idx >> 13) & 63;
    const int dt2 = idx >> 19;
    const int d = dt2 * 256 + dd;
    const int c = ks * 32 + cg * 8 + c8;
    Ah[idx] = __float2half(W1[(size_t)(HID_ + c) * HID_ + d]);
}

// ---------------------------------------------------------------------------
// K0b: pack B = spT (c x j) into fp16 K-step chunks — LDS-free.
// Chunk (jt2, ks): 32 c x 256 j, layout [cg(4)][jj(256)][c8(8)] = 8192 halfs.
// ---------------------------------------------------------------------------
__global__ __launch_bounds__(256) void k0b_packB(
    const float* __restrict__ spatial, __half* __restrict__ Bh)
{
    const int jt2 = blockIdx.x;           // 0..195
    const int ks  = blockIdx.y;           // 0..63
    const int jj  = threadIdx.x;          // 0..255

    const int j = jt2 * 256 + jj;
    const int b = j / N_;
    const int n = j - b * N_;
    const float* spj = spatial + (size_t)b * SPB_ + n;
    __half* outb = Bh + (((size_t)jt2 * 64 + ks) * 4) * 2048 + jj * 8;

#pragma unroll
    for (int cg = 0; cg < 4; ++cg) {
        const float* src = spj + (size_t)(ks * 32 + cg * 8) * N_;
        f16x8 v;
#pragma unroll
        for (int c8 = 0; c8 < 8; ++c8)
            v[c8] = (_Float16)src[(size_t)c8 * N_];
        *(f16x8*)(outb + (size_t)cg * 2048) = v;
    }
}

// ---------------------------------------------------------------------------
// K2 (phase-split pipelined MFMA): 256x256 block tile, 8 waves (2Mx4N),
// per-wave 128x64 (R8 geometry: 2 waves/SIMD, VGPR ~190, no spill).
// BK=32, full K=2048 (64 steps), 4-slot LDS ring (128 KB), stage-ahead-2.
// m201-style per-step TWO phases:
//   P0: ds_read A0-3,B0-3 | stage 2 A-gloads | barrier | lgkm0 | 16 MFMA
//   P1: ds_read A4-7      | stage 2 B-gloads | vmcnt(4) | barrier | lgkm0 | 16 MFMA
// vmcnt(4) (never 0 in-loop) confirms slot kt+1 one step before its reads.
// Slot write-after-read separated by >=2 barriers. Fused tanh epilogue.
// ---------------------------------------------------------------------------
__global__ __launch_bounds__(512, 2) void k2_pipe(
    const __half* __restrict__ Ah, const __half* __restrict__ Bh,
    const float* __restrict__ W2, const float* __restrict__ h1,
    float* __restrict__ ps)
{
    extern __shared__ __align__(16) short ldsb[];   // 4 * 16384 halfs = 128 KB

    const int tid = threadIdx.x;
    const int l  = tid & 63;
    const int w  = tid >> 6;            // wave 0..7
    const int wm = w >> 2;              // 0..1  (d half: 128 rows)
    const int wn = w & 3;               // 0..3  (j quarter: 64 cols)
    const int cg = l >> 4;              // 0..3
    const int rr = l & 15;

    // bijective XCD-chunked swizzle: 784 = 8 * 98; dt2 fastest in chunk.
    const int orig = blockIdx.x;
    const int wgid = (orig & 7) * 98 + (orig >> 3);
    const int jt2 = wgid >> 2;          // 0..195
    const int dt2 = wgid & 3;           // 0..3

    const __half* apack = Ah + ((size_t)dt2 * 64) * 8192;
    const __half* bpack = Bh + ((size_t)jt2 * 64) * 8192;

    f32x4 acc[8][4] = {};

    // per-wave: 2 A-gloads (P0), 2 B-gloads (P1)
#define STAGE_A(KT, SLOT) do {                                                  \
        const __half* as_ = apack + (size_t)(KT) * 8192;                        \
        short* ad_ = ldsb + (SLOT) * 16384 + w * 1024;                          \
        __builtin_amdgcn_global_load_lds(GLOBAL_AS(as_ + w * 1024 + l * 8),     \
                                         LDS_AS(ad_), 16, 0, 0);                \
        __builtin_amdgcn_global_load_lds(GLOBAL_AS(as_ + w * 1024 + 512 + l * 8),\
                                         LDS_AS(ad_ + 512), 16, 0, 0);          \
    } while (0)

#define STAGE_B(KT, SLOT) do {                                                  \
        const __half* bs_ = bpack + (size_t)(KT) * 8192;                        \
        short* bd_ = ldsb + (SLOT) * 16384 + 8192 + w * 1024;                   \
        __builtin_amdgcn_global_load_lds(GLOBAL_AS(bs_ + w * 1024 + l * 8),     \
                                         LDS_AS(bd_), 16, 0, 0);                \
        __builtin_amdgcn_global_load_lds(GLOBAL_AS(bs_ + w * 1024 + 512 + l * 8),\
                                         LDS_AS(bd_ + 512), 16, 0, 0);          \
    } while (0)

#define STEP(KT, DO_STAGE, VMC) do {                                            \
        const short* ab_ = ldsb + ((KT) & 3) * 16384;                           \
        const short* bb_ = ab_ + 8192;                                          \
        f16x8 af[4], bf[4], af2[4];                                             \
        _Pragma("unroll")                                                       \
        for (int ni = 0; ni < 4; ++ni)                                          \
            bf[ni] = *(const f16x8*)&bb_[(cg * 256 + wn * 64 + ni * 16 + rr) * 8];\
        _Pragma("unroll")                                                       \
        for (int mi = 0; mi < 4; ++mi)                                          \
            af[mi] = *(const f16x8*)&ab_[(cg * 256 + wm * 128 + mi * 16 + rr) * 8];\
        if (DO_STAGE) STAGE_A((KT) + 2, ((KT) + 2) & 3);                        \
        __builtin_amdgcn_s_barrier();                                           \
        asm volatile("s_waitcnt lgkmcnt(0)" ::: "memory");                      \
        __builtin_amdgcn_sched_barrier(0);                                      \
        __builtin_amdgcn_s_setprio(1);                                          \
        _Pragma("unroll")                                                       \
        for (int mi = 0; mi < 4; ++mi)                                          \
            _Pragma("unroll")                                                   \
            for (int ni = 0; ni < 4; ++ni)                                      \
                acc[mi][ni] = __builtin_amdgcn_mfma_f32_16x16x32_f16(           \
                    af[mi], bf[ni], acc[mi][ni], 0, 0, 0);                      \
        __builtin_amdgcn_s_setprio(0);                                          \
        _Pragma("unroll")                                                       \
        for (int mi = 0; mi < 4; ++mi)                                          \
            af2[mi] = *(const f16x8*)&ab_[(cg * 256 + wm * 128 + (mi + 4) * 16 + rr) * 8];\
        if (DO_STAGE) STAGE_B((KT) + 2, ((KT) + 2) & 3);                        \
        asm volatile("s_waitcnt vmcnt(" #VMC ")" ::: "memory");                 \
        __builtin_amdgcn_s_barrier();                                           \
        asm volatile("s_waitcnt lgkmcnt(0)" ::: "memory");                      \
        __builtin_amdgcn_sched_barrier(0);                                      \
        __builtin_amdgcn_s_setprio(1);                                          \
        _Pragma("unroll")                                                       \
        for (int mi = 0; mi < 4; ++mi)                                          \
            _Pragma("unroll")                                                   \
            for (int ni = 0; ni < 4; ++ni)                                      \
                acc[mi + 4][ni] = __builtin_amdgcn_mfma_f32_16x16x32_f16(       \
                    af2[mi], bf[ni], acc[mi + 4][ni], 0, 0, 0);                 \
        __builtin_amdgcn_s_setprio(0);                                          \
    } while (0)

    // prologue: stage slots 0,1; confirm slot 0 (keep newest 4 = slot 1)
    STAGE_A(0, 0); STAGE_B(0, 0);
    STAGE_A(1, 1); STAGE_B(1, 1);
    asm volatile("s_waitcnt vmcnt(4)" ::: "memory");
    __builtin_amdgcn_s_barrier();

#pragma unroll 1
    for (int kt = 0; kt < 60; kt += 4) {
        STEP(kt + 0, true, 4);
        STEP(kt + 1, true, 4);
        STEP(kt + 2, true, 4);
        STEP(kt + 3, true, 4);
    }
    STEP(60, true, 4);
    STEP(61, true, 4);   // stages slot 63; vmcnt(4) confirms slot 62
    STEP(62, false, 0);  // confirm slot 63
    STEP(63, false, 0);

#undef STAGE_A
#undef STAGE_B
#undef STEP

    // Epilogue: partial[j] = sum_{d in this block's 256} tanh(acc + h1) * w2
    const int dbase = dt2 * 256 + wm * 128;
    float w2v[8][4];
#pragma unroll
    for (int mi = 0; mi < 8; ++mi)
#pragma unroll
        for (int q = 0; q < 4; ++q)
            w2v[mi][q] = W2[dbase + mi * 16 + cg * 4 + q];

    float partial[4];
#pragma unroll
    for (int ni = 0; ni < 4; ++ni) {
        const int j = jt2 * 256 + wn * 64 + ni * 16 + rr;
        const int bj = j / N_;
        const float* h1p = h1 + (size_t)bj * HID_ + dbase;
        float s = 0.f;
#pragma unroll
        for (int mi = 0; mi < 8; ++mi)
#pragma unroll
            for (int q = 0; q < 4; ++q)
                s += fast_tanh(acc[mi][ni][q] + h1p[mi * 16 + cg * 4 + q]) * w2v[mi][q];
        partial[ni] = s;
    }

    float* red = (float*)ldsb;
    __syncthreads();                 // all waves done with ring LDS reads
    if (tid < 256) red[tid] = 0.f;
    __syncthreads();
#pragma unroll
    for (int ni = 0; ni < 4; ++ni)
        atomicAdd(&red[wn * 64 + ni * 16 + rr], partial[ni]);
    __syncthreads();
    if (tid < 256)
        ps[(size_t)dt2 * NJ_ + (size_t)jt2 * 256 + tid] = red[tid];
}

// ---------------------------------------------------------------------------
// K2 fallback (fp32 vector path) if workspace is too small for packing.
// ---------------------------------------------------------------------------
__global__ __launch_bounds__(256) void k2_fb(
    const float* __restrict__ spatial, const float* __restrict__ W1,
    const float* __restrict__ W2, const float* __restrict__ h1,
    float* __restrict__ ps)
{
    __shared__ float As[32][64];
    __shared__ float Bs[32][64];
    const int t = threadIdx.x;
    const int d0 = blockIdx.x * 64;
    const int j0 = blockIdx.y * 64;
    const int ld = t & 63, lk = t >> 6;
    const float* Aptr = W1 + (size_t)(HID_ + lk) * HID_ + (d0 + ld);
    const int j = j0 + ld;
    const int bb = j / N_, nn = j - bb * N_;
    const float* Bptr = spatial + (size_t)bb * SPB_ + (size_t)lk * N_ + nn;
    const int tr = t >> 4, tc = t & 15;
    float acc[4][4] = {};
    for (int c0 = 0; c0 < SP_; c0 += 32) {
#pragma unroll
        for (int i = 0; i < 8; ++i) {
            As[lk + 4 * i][ld] = Aptr[(size_t)(c0 + 4 * i) * HID_];
            Bs[lk + 4 * i][ld] = Bptr[(size_t)(c0 + 4 * i) * N_];
        }
        __syncthreads();
#pragma unroll
        for (int k = 0; k < 32; ++k) {
            float av[4], bv[4];
            *(float4*)av = *(const float4*)&As[k][tr * 4];
            *(float4*)bv = *(const float4*)&Bs[k][tc * 4];
#pragma unroll
            for (int di = 0; di < 4; ++di)
#pragma unroll
                for (int ji = 0; ji < 4; ++ji)
                    acc[di][ji] += av[di] * bv[ji];
        }
        __syncthreads();
    }
    float w2v[4];
#pragma unroll
    for (int di = 0; di < 4; ++di) w2v[di] = W2[d0 + tr * 4 + di];
    float partial[4] = {};
#pragma unroll
    for (int ji = 0; ji < 4; ++ji) {
        const int jg = j0 + tc * 4 + ji;
        const int bj = jg / N_;
        const float* h1row = h1 + (size_t)bj * HID_ + d0 + tr * 4;
#pragma unroll
        for (int di = 0; di < 4; ++di)
            partial[ji] += tanhf(acc[di][ji] + h1row[di]) * w2v[di];
    }
    __shared__ float red[64];
    if (t < 64) red[t] = 0.f;
    __syncthreads();
#pragma unroll
    for (int ji = 0; ji < 4; ++ji)
        atomicAdd(&red[tc * 4 + ji], partial[ji]);
    __syncthreads();
    if (t < 64)
        ps[(size_t)blockIdx.x * NJ_ + j0 + t] = red[t];
}

// ---------------------------------------------------------------------------
// K3: scores[b,n] = sum_slices ps; attn = softmax_n  (b2 shift-invariant)
// ---------------------------------------------------------------------------
__global__ __launch_bounds__(256) void k3_softmax(
    const float* __restrict__ ps, float* __restrict__ attn, int nslices)
{
    const int b = blockIdx.x;
    const int t = threadIdx.x;
    __shared__ float sdata[256];

    float s = -1e30f;
    if (t < N_) {
        s = 0.f;
        for (int dt = 0; dt < nslices; ++dt)
            s += ps[(size_t)dt * NJ_ + b * N_ + t];
    }
    sdata[t] = s;
    __syncthreads();
    for (int off = 128; off > 0; off >>= 1) {
        if (t < off) sdata[t] = fmaxf(sdata[t], sdata[t + off]);
        __syncthreads();
    }
    const float m = sdata[0];
    __syncthreads();
    const float e = (t < N_) ? expf(s - m) : 0.f;
    sdata[t] = e;
    __syncthreads();
    for (int off = 128; off > 0; off >>= 1) {
        if (t < off) sdata[t] += sdata[t + off];
        __syncthreads();
    }
    const float inv = 1.f / sdata[0];
    if (t < N_) attn[(size_t)b * N_ + t] = e * inv;
}

// ---------------------------------------------------------------------------
// K4: context[b,c] = sum_n attn[b,n] * spatial[b, c*196 + n]
// 196 = 49 float4 (row base 784 B, 16B-aligned). One wave per (b,c).
// ---------------------------------------------------------------------------
__global__ __launch_bounds__(256) void k4_context(
    const float* __restrict__ spatial, const float* __restrict__ attn,
    float* __restrict__ ctx)
{
    const int wid = (blockIdx.x * 256 + threadIdx.x) >> 6;
    const int lane = threadIdx.x & 63;
    const int b = wid >> 11;
    const int c = wid & 2047;
    const float* sp = spatial + (size_t)b * SPB_ + (size_t)c * N_;
    const float* at = attn + (size_t)b * N_;

    float sum = 0.f;
    if (lane < 49) {
        const float4 s4 = ((const float4*)sp)[lane];
        const float4 a4 = ((const float4*)at)[lane];
        sum = s4.x * a4.x + s4.y * a4.y + s4.z * a4.z + s4.w * a4.w;
    }
#pragma unroll
    for (int off = 32; off > 0; off >>= 1)
        sum += __shfl_down(sum, off, 64);
    if (lane == 0)
        ctx[(size_t)b * 2048 + c] = sum;
}

// ---------------------------------------------------------------------------
extern "C" void kernel_launch(void* const* d_in, const int* in_sizes, int n_in,
                              void* d_out, int out_size, void* d_ws, size_t ws_size,
                              hipStream_t stream)
{
    const float* hidden  = (const float*)d_in[0];
    const float* spatial = (const float*)d_in[1];
    const float* W1      = (const float*)d_in[2];
    const float* b1      = (const float*)d_in[3];
    const float* W2      = (const float*)d_in[4];
    // b2 unused: softmax shift-invariant.

    float* out_ctx  = (float*)d_out;
    float* out_attn = (float*)d_out + (size_t)B_ * 2048;

    char* ws = (char*)d_ws;
    float* h1 = (float*)ws;                               // 1 MB
    float* psb = (float*)(ws + (1u << 20));               // 4-16 slices (3.2 MB)

    // MFMA-path workspace layout
    const size_t offAh = 8u << 20;                         // 4 MB
    const size_t offBh = 16u << 20;                        // 205 MB
    const size_t szB   = (size_t)196 * 64 * 8192 * 2;      // 205,520,896 B
    const size_t needed = offBh + szB;                     // ~212 MB

    k1_h1<<<dim3(4, 64), 256, 0, stream>>>(hidden, W1, b1, h1);

    if (ws_size >= needed) {
        __half* Ah = (__half*)(ws + offAh);
        __half* Bh = (__half*)(ws + offBh);
        k0a_packA<<<dim3(8192), 256, 0, stream>>>(W1, Ah);
        k0b_packB<<<dim3(196, 64), 256, 0, stream>>>(spatial, Bh);
        (void)hipFuncSetAttribute((const void*)k2_pipe,
                                  hipFuncAttributeMaxDynamicSharedMemorySize,
                                  131072);
        k2_pipe<<<dim3(784), 512, 131072, stream>>>(Ah, Bh, W2, h1, psb);
        k3_softmax<<<dim3(B_), 256, 0, stream>>>(psb, out_attn, 4);
    } else {
        k2_fb<<<dim3(16, 784), 256, 0, stream>>>(spatial, W1, W2, h1, psb);
        k3_softmax<<<dim3(B_), 256, 0, stream>>>(psb, out_attn, 16);
    }
    k4_context<<<dim3((B_ * 2048) / 4), 256, 0, stream>>>(spatial, out_attn, out_ctx);
}

// Round 12
// 517.116 us; speedup vs baseline: 1.1024x; 1.0426x over previous
//
#include <hip/hip_runtime.h>
#include <hip/hip_bf16.h>
#include <hip/hip_fp16.h>
#include <math.h>

// Problem constants
#define B_   256
#define HID_ 1024
#define SP_  2048
#define N_   196        // 14*14
#define NJ_  (B_ * N_)  // 50176 = 196 * 256
#define SPB_ (SP_ * N_) // elems per batch of spatial

typedef float    f32x4 __attribute__((ext_vector_type(4)));
typedef _Float16 f16x8 __attribute__((ext_vector_type(8)));

#define GLOBAL_AS(p) ((const __attribute__((address_space(1))) void*)(p))
#define LDS_AS(p)    ((__attribute__((address_space(3))) void*)(p))

__device__ __forceinline__ float fast_tanh(float x) {
    const float e = exp2f(x * 2.8853900817779268f);  // 2*log2(e)
    return 1.f - 2.f / (e + 1.f);
}

// ---------------------------------------------------------------------------
// K1: h1[b,d] = hidden @ W1h + b1   (256x1024 @ 1024x1024)
// ---------------------------------------------------------------------------
__global__ __launch_bounds__(256) void k1_h1(
    const float* __restrict__ hidden, const float* __restrict__ W1,
    const float* __restrict__ b1, float* __restrict__ h1)
{
    __shared__ float hs[4][HID_];
    const int t = threadIdx.x;
    const int d = blockIdx.x * 256 + t;
    const int b0 = blockIdx.y * 4;

    for (int i = t; i < 4 * HID_; i += 256)
        hs[i >> 10][i & 1023] = hidden[(size_t)(b0 + (i >> 10)) * HID_ + (i & 1023)];
    __syncthreads();

    float acc[4] = {};
    for (int h = 0; h < HID_; ++h) {
        const float w = W1[(size_t)h * HID_ + d];
#pragma unroll
        for (int i = 0; i < 4; ++i) acc[i] += hs[i][h] * w;
    }
    const float bias = b1[d];
#pragma unroll
    for (int i = 0; i < 4; ++i)
        h1[(size_t)(b0 + i) * HID_ + d] = acc[i] + bias;
}

// ---------------------------------------------------------------------------
// K0a: pack A = W1s^T (d x c, 1024x2048) into fp16 K-step chunks.
// Chunk (dt, ks): 128 d x 32 c, layout [cg(4)][dd(128)][c8(8)] = 4096 halfs.
// Global order: [dt(8)][ks(64)][chunk 4096] — linear idx == dest idx.
// ---------------------------------------------------------------------------
__global__ __launch_bounds__(256) void k0a_packA(
    const float* __restrict__ W1, __half* __restrict__ Ah)
{
    const size_t idx = (size_t)blockIdx.x * 256 + threadIdx.x;  // < 2,097,152
    const int c8 = idx & 7;
    const int dd = (idx >> 3) & 127;
    const int cg = (idx >> 10) & 3;
    const int ks = (idx >> 12) & 63;
    const int dt = idx >> 18;
    const int d = dt * 128 + dd;
    const int c = ks * 32 + cg * 8 + c8;
    Ah[idx] = __float2half(W1[(size_t)(HID_ + c) * HID_ + d]);
}

// ---------------------------------------------------------------------------
// K0b: pack B = spT (c x j) into fp16 K-step chunks — LDS-free.
// Chunk (jt2, ks): 32 c x 256 j, layout [cg(4)][jj(256)][c8(8)] = 8192 halfs.
// ---------------------------------------------------------------------------
__global__ __launch_bounds__(256) void k0b_packB(
    const float* __restrict__ spatial, __half* __restrict__ Bh)
{
    const int jt2 = blockIdx.x;           // 0..195
    const int ks  = blockIdx.y;           // 0..63
    const int jj  = threadIdx.x;          // 0..255

    const int j = jt2 * 256 + jj;
    const int b = j / N_;
    const int n = j - b * N_;
    const float* spj = spatial + (size_t)b * SPB_ + n;
    __half* outb = Bh + (((size_t)jt2 * 64 + ks) * 4) * 2048 + jj * 8;

#pragma unroll
    for (int cg = 0; cg < 4; ++cg) {
        const float* src = spj + (size_t)(ks * 32 + cg * 8) * N_;
        f16x8 v;
#pragma unroll
        for (int c8 = 0; c8 < 8; ++c8)
            v[c8] = (_Float16)src[(size_t)c8 * N_];
        *(f16x8*)(outb + (size_t)cg * 2048) = v;
    }
}

// ---------------------------------------------------------------------------
// K2 (phase-split pipelined MFMA, v3): 128d x 256j block tile, 4 waves
// (2M x 2N), per-wave 64x128 (same 12-read/32-MFMA ratio as R11).
// 3-slot LDS ring (72 KB) -> TWO blocks/CU (cross-block overlap + smooth
// tail: 1568 blocks at 2/CU vs R11's 784 at 1/CU with 23% tail idle).
// BK=32, full K=2048 per block (tanh epilogue needs complete c-reduction).
// Per-step two phases, counted vmcnt(6) (6 gloads/wave/step, stage-ahead-2).
// Hazard: slot (kt+2)%3 last read at step kt-1, restaged at kt — separated
// by the P1(kt-1) barrier. vmcnt(6) leaves kt+2's 6 in flight, confirms kt+1.
// ---------------------------------------------------------------------------
__global__ __launch_bounds__(256, 2) void k2_pipe(
    const __half* __restrict__ Ah, const __half* __restrict__ Bh,
    const float* __restrict__ W2, const float* __restrict__ h1,
    float* __restrict__ ps)
{
    extern __shared__ __align__(16) short ldsb[];   // 3 * 12288 halfs = 72 KB

    const int tid = threadIdx.x;
    const int l  = tid & 63;
    const int w  = tid >> 6;            // wave 0..3
    const int wm = w >> 1;              // 0..1  (d half: 64 rows)
    const int wn = w & 1;               // 0..1  (j half: 128 cols)
    const int cg = l >> 4;              // 0..3
    const int rr = l & 15;

    // bijective XCD-chunked swizzle: 1568 = 8 * 196; dt fastest in chunk ->
    // the 8 same-jt2 blocks land on one XCD (B panel 1 MB reused x8 in L2).
    const int orig = blockIdx.x;
    const int wgid = (orig & 7) * 196 + (orig >> 3);
    const int jt2 = wgid >> 3;          // 0..195
    const int dt  = wgid & 7;           // 0..7

    const __half* apack = Ah + ((size_t)dt * 64) * 4096;
    const __half* bpack = Bh + ((size_t)jt2 * 64) * 8192;

    f32x4 acc[4][8] = {};

    // per wave per step: A 2 gloads (P0), B 4 gloads (P1)
#define STAGE_A(KT, SLOT) do {                                                  \
        const __half* as_ = apack + (size_t)(KT) * 4096;                        \
        short* ad_ = ldsb + (SLOT) * 12288 + w * 1024;                          \
        __builtin_amdgcn_global_load_lds(GLOBAL_AS(as_ + w * 1024 + l * 8),     \
                                         LDS_AS(ad_), 16, 0, 0);                \
        __builtin_amdgcn_global_load_lds(GLOBAL_AS(as_ + w * 1024 + 512 + l * 8),\
                                         LDS_AS(ad_ + 512), 16, 0, 0);          \
    } while (0)

#define STAGE_B(KT, SLOT) do {                                                  \
        const __half* bs_ = bpack + (size_t)(KT) * 8192;                        \
        short* bd_ = ldsb + (SLOT) * 12288 + 4096 + w * 2048;                   \
        _Pragma("unroll")                                                       \
        for (int i_ = 0; i_ < 4; ++i_)                                          \
            __builtin_amdgcn_global_load_lds(                                   \
                GLOBAL_AS(bs_ + w * 2048 + i_ * 512 + l * 8),                   \
                LDS_AS(bd_ + i_ * 512), 16, 0, 0);                              \
    } while (0)

#define STEP(KT, CSLOT, SSLOT, DO_STAGE, VMC) do {                              \
        const short* ab_ = ldsb + (CSLOT) * 12288;                              \
        const short* bb_ = ab_ + 4096;                                          \
        f16x8 af[2], bf[8], af2[2];                                             \
        _Pragma("unroll")                                                       \
        for (int ni = 0; ni < 8; ++ni)                                          \
            bf[ni] = *(const f16x8*)&bb_[(cg * 256 + wn * 128 + ni * 16 + rr) * 8];\
        _Pragma("unroll")                                                       \
        for (int mi = 0; mi < 2; ++mi)                                          \
            af[mi] = *(const f16x8*)&ab_[(cg * 128 + wm * 64 + mi * 16 + rr) * 8];\
        if (DO_STAGE) STAGE_A((KT) + 2, SSLOT);                                 \
        __builtin_amdgcn_s_barrier();                                           \
        asm volatile("s_waitcnt lgkmcnt(0)" ::: "memory");                      \
        __builtin_amdgcn_sched_barrier(0);                                      \
        __builtin_amdgcn_s_setprio(1);                                          \
        _Pragma("unroll")                                                       \
        for (int mi = 0; mi < 2; ++mi)                                          \
            _Pragma("unroll")                                                   \
            for (int ni = 0; ni < 8; ++ni)                                      \
                acc[mi][ni] = __builtin_amdgcn_mfma_f32_16x16x32_f16(           \
                    af[mi], bf[ni], acc[mi][ni], 0, 0, 0);                      \
        __builtin_amdgcn_s_setprio(0);                                          \
        _Pragma("unroll")                                                       \
        for (int mi = 0; mi < 2; ++mi)                                          \
            af2[mi] = *(const f16x8*)&ab_[(cg * 128 + wm * 64 + (mi + 2) * 16 + rr) * 8];\
        if (DO_STAGE) STAGE_B((KT) + 2, SSLOT);                                 \
        asm volatile("s_waitcnt vmcnt(" #VMC ")" ::: "memory");                 \
        __builtin_amdgcn_s_barrier();                                           \
        asm volatile("s_waitcnt lgkmcnt(0)" ::: "memory");                      \
        __builtin_amdgcn_sched_barrier(0);                                      \
        __builtin_amdgcn_s_setprio(1);                                          \
        _Pragma("unroll")                                                       \
        for (int mi = 0; mi < 2; ++mi)                                          \
            _Pragma("unroll")                                                   \
            for (int ni = 0; ni < 8; ++ni)                                      \
                acc[mi + 2][ni] = __builtin_amdgcn_mfma_f32_16x16x32_f16(       \
                    af2[mi], bf[ni], acc[mi + 2][ni], 0, 0, 0);                 \
        __builtin_amdgcn_s_setprio(0);                                          \
    } while (0)

    // prologue: stage slots 0,1 fully; confirm slot 0
    STAGE_A(0, 0); STAGE_B(0, 0);
    STAGE_A(1, 1); STAGE_B(1, 1);
    asm volatile("s_waitcnt vmcnt(6)" ::: "memory");
    __builtin_amdgcn_s_barrier();

#pragma unroll 1
    for (int kt = 0; kt < 60; kt += 3) {
        STEP(kt + 0, 0, 2, true, 6);
        STEP(kt + 1, 1, 0, true, 6);
        STEP(kt + 2, 2, 1, true, 6);
    }
    STEP(60, 0, 2, true, 6);   // stages 62 -> slot 2
    STEP(61, 1, 0, true, 6);   // stages 63 -> slot 0; vmcnt(6) confirms 62
    STEP(62, 2, 0, false, 0);  // vmcnt(0) confirms 63
    STEP(63, 0, 0, false, 0);

#undef STAGE_A
#undef STAGE_B
#undef STEP

    // Epilogue: partial[j] = sum_{d in this block's 128} tanh(acc + h1) * w2
    const int dbase = dt * 128 + wm * 64;
    float w2v[4][4];
#pragma unroll
    for (int mi = 0; mi < 4; ++mi)
#pragma unroll
        for (int q = 0; q < 4; ++q)
            w2v[mi][q] = W2[dbase + mi * 16 + cg * 4 + q];

    float partial[8];
#pragma unroll
    for (int ni = 0; ni < 8; ++ni) {
        const int j = jt2 * 256 + wn * 128 + ni * 16 + rr;
        const int bj = j / N_;
        const float* h1p = h1 + (size_t)bj * HID_ + dbase;
        float s = 0.f;
#pragma unroll
        for (int mi = 0; mi < 4; ++mi)
#pragma unroll
            for (int q = 0; q < 4; ++q)
                s += fast_tanh(acc[mi][ni][q] + h1p[mi * 16 + cg * 4 + q]) * w2v[mi][q];
        partial[ni] = s;
    }

    float* red = (float*)ldsb;
    __syncthreads();                 // all waves done with ring LDS reads
    red[tid] = 0.f;
    __syncthreads();
#pragma unroll
    for (int ni = 0; ni < 8; ++ni)
        atomicAdd(&red[wn * 128 + ni * 16 + rr], partial[ni]);
    __syncthreads();
    ps[(size_t)dt * NJ_ + (size_t)jt2 * 256 + tid] = red[tid];
}

// ---------------------------------------------------------------------------
// K2 fallback (fp32 vector path) if workspace is too small for packing.
// ---------------------------------------------------------------------------
__global__ __launch_bounds__(256) void k2_fb(
    const float* __restrict__ spatial, const float* __restrict__ W1,
    const float* __restrict__ W2, const float* __restrict__ h1,
    float* __restrict__ ps)
{
    __shared__ float As[32][64];
    __shared__ float Bs[32][64];
    const int t = threadIdx.x;
    const int d0 = blockIdx.x * 64;
    const int j0 = blockIdx.y * 64;
    const int ld = t & 63, lk = t >> 6;
    const float* Aptr = W1 + (size_t)(HID_ + lk) * HID_ + (d0 + ld);
    const int j = j0 + ld;
    const int bb = j / N_, nn = j - bb * N_;
    const float* Bptr = spatial + (size_t)bb * SPB_ + (size_t)lk * N_ + nn;
    const int tr = t >> 4, tc = t & 15;
    float acc[4][4] = {};
    for (int c0 = 0; c0 < SP_; c0 += 32) {
#pragma unroll
        for (int i = 0; i < 8; ++i) {
            As[lk + 4 * i][ld] = Aptr[(size_t)(c0 + 4 * i) * HID_];
            Bs[lk + 4 * i][ld] = Bptr[(size_t)(c0 + 4 * i) * N_];
        }
        __syncthreads();
#pragma unroll
        for (int k = 0; k < 32; ++k) {
            float av[4], bv[4];
            *(float4*)av = *(const float4*)&As[k][tr * 4];
            *(float4*)bv = *(const float4*)&Bs[k][tc * 4];
#pragma unroll
            for (int di = 0; di < 4; ++di)
#pragma unroll
                for (int ji = 0; ji < 4; ++ji)
                    acc[di][ji] += av[di] * bv[ji];
        }
        __syncthreads();
    }
    float w2v[4];
#pragma unroll
    for (int di = 0; di < 4; ++di) w2v[di] = W2[d0 + tr * 4 + di];
    float partial[4] = {};
#pragma unroll
    for (int ji = 0; ji < 4; ++ji) {
        const int jg = j0 + tc * 4 + ji;
        const int bj = jg / N_;
        const float* h1row = h1 + (size_t)bj * HID_ + d0 + tr * 4;
#pragma unroll
        for (int di = 0; di < 4; ++di)
            partial[ji] += tanhf(acc[di][ji] + h1row[di]) * w2v[di];
    }
    __shared__ float red[64];
    if (t < 64) red[t] = 0.f;
    __syncthreads();
#pragma unroll
    for (int ji = 0; ji < 4; ++ji)
        atomicAdd(&red[tc * 4 + ji], partial[ji]);
    __syncthreads();
    if (t < 64)
        ps[(size_t)blockIdx.x * NJ_ + j0 + t] = red[t];
}

// ---------------------------------------------------------------------------
// K3: scores[b,n] = sum_slices ps; attn = softmax_n  (b2 shift-invariant)
// ---------------------------------------------------------------------------
__global__ __launch_bounds__(256) void k3_softmax(
    const float* __restrict__ ps, float* __restrict__ attn, int nslices)
{
    const int b = blockIdx.x;
    const int t = threadIdx.x;
    __shared__ float sdata[256];

    float s = -1e30f;
    if (t < N_) {
        s = 0.f;
        for (int dt = 0; dt < nslices; ++dt)
            s += ps[(size_t)dt * NJ_ + b * N_ + t];
    }
    sdata[t] = s;
    __syncthreads();
    for (int off = 128; off > 0; off >>= 1) {
        if (t < off) sdata[t] = fmaxf(sdata[t], sdata[t + off]);
        __syncthreads();
    }
    const float m = sdata[0];
    __syncthreads();
    const float e = (t < N_) ? expf(s - m) : 0.f;
    sdata[t] = e;
    __syncthreads();
    for (int off = 128; off > 0; off >>= 1) {
        if (t < off) sdata[t] += sdata[t + off];
        __syncthreads();
    }
    const float inv = 1.f / sdata[0];
    if (t < N_) attn[(size_t)b * N_ + t] = e * inv;
}

// ---------------------------------------------------------------------------
// K4: context[b,c] = sum_n attn[b,n] * spatial[b, c*196 + n]
// 196 = 49 float4 (row base 784 B, 16B-aligned). One wave per (b,c).
// ---------------------------------------------------------------------------
__global__ __launch_bounds__(256) void k4_context(
    const float* __restrict__ spatial, const float* __restrict__ attn,
    float* __restrict__ ctx)
{
    const int wid = (blockIdx.x * 256 + threadIdx.x) >> 6;
    const int lane = threadIdx.x & 63;
    const int b = wid >> 11;
    const int c = wid & 2047;
    const float* sp = spatial + (size_t)b * SPB_ + (size_t)c * N_;
    const float* at = attn + (size_t)b * N_;

    float sum = 0.f;
    if (lane < 49) {
        const float4 s4 = ((const float4*)sp)[lane];
        const float4 a4 = ((const float4*)at)[lane];
        sum = s4.x * a4.x + s4.y * a4.y + s4.z * a4.z + s4.w * a4.w;
    }
#pragma unroll
    for (int off = 32; off > 0; off >>= 1)
        sum += __shfl_down(sum, off, 64);
    if (lane == 0)
        ctx[(size_t)b * 2048 + c] = sum;
}

// ---------------------------------------------------------------------------
extern "C" void kernel_launch(void* const* d_in, const int* in_sizes, int n_in,
                              void* d_out, int out_size, void* d_ws, size_t ws_size,
                              hipStream_t stream)
{
    const float* hidden  = (const float*)d_in[0];
    const float* spatial = (const float*)d_in[1];
    const float* W1      = (const float*)d_in[2];
    const float* b1      = (const float*)d_in[3];
    const float* W2      = (const float*)d_in[4];
    // b2 unused: softmax shift-invariant.

    float* out_ctx  = (float*)d_out;
    float* out_attn = (float*)d_out + (size_t)B_ * 2048;

    char* ws = (char*)d_ws;
    float* h1 = (float*)ws;                               // 1 MB
    float* psb = (float*)(ws + (1u << 20));               // 8 slices (1.6 MB)

    // MFMA-path workspace layout
    const size_t offAh = 8u << 20;                         // 4 MB
    const size_t offBh = 16u << 20;                        // 205 MB
    const size_t szB   = (size_t)196 * 64 * 8192 * 2;      // 205,520,896 B
    const size_t needed = offBh + szB;                     // ~212 MB

    k1_h1<<<dim3(4, 64), 256, 0, stream>>>(hidden, W1, b1, h1);

    if (ws_size >= needed) {
        __half* Ah = (__half*)(ws + offAh);
        __half* Bh = (__half*)(ws + offBh);
        k0a_packA<<<dim3(8192), 256, 0, stream>>>(W1, Ah);
        k0b_packB<<<dim3(196, 64), 256, 0, stream>>>(spatial, Bh);
        (void)hipFuncSetAttribute((const void*)k2_pipe,
                                  hipFuncAttributeMaxDynamicSharedMemorySize,
                                  73728);
        k2_pipe<<<dim3(1568), 256, 73728, stream>>>(Ah, Bh, W2, h1, psb);
        k3_softmax<<<dim3(B_), 256, 0, stream>>>(psb, out_attn, 8);
    } else {
        k2_fb<<<dim3(16, 784), 256, 0, stream>>>(spatial, W1, W2, h1, psb);
        k3_softmax<<<dim3(B_), 256, 0, stream>>>(psb, out_attn, 16);
    }
    k4_context<<<dim3((B_ * 2048) / 4), 256, 0, stream>>>(spatial, out_attn, out_ctx);
}